// Round 12
// baseline (396.990 us; speedup 1.0000x reference)
//
#include <hip/hip_runtime.h>

#define D_MODEL 768
#define D_INNER 1536
#define D_STATE 16
#define DT_RANK 96
#define BB 2
#define LL 2048
#define TT (BB*LL)          // 4096 tokens
#define NC 64               // chunks per sequence
#define CL 32               // chunk length
#define SKK 4               // split-K factor for xdbl GEMM
#define LOG2E 1.44269504f

typedef unsigned short u16;
typedef short bf16x8 __attribute__((ext_vector_type(8)));
typedef float f32x4  __attribute__((ext_vector_type(4)));

__device__ __forceinline__ float bf2f(u16 u) {
    union { unsigned int i; float f; } c; c.i = ((unsigned int)u) << 16; return c.f;
}
__device__ __forceinline__ u16 f2bf(float f) {
    union { float f; unsigned int i; } c; c.f = f;
    unsigned int x = c.i;
    return (u16)((x + 0x7fffu + ((x >> 16) & 1u)) >> 16);   // RNE
}
__device__ __forceinline__ float bfu_lo(unsigned int u) {
    union { unsigned int i; float f; } c; c.i = u << 16; return c.f;
}
__device__ __forceinline__ float bfu_hi(unsigned int u) {
    union { unsigned int i; float f; } c; c.i = u & 0xFFFF0000u; return c.f;
}
__device__ __forceinline__ float ldx(const void* p, size_t i, bool f32) {
    return f32 ? ((const float*)p)[i] : bf2f(((const u16*)p)[i]);
}
// async global->LDS DMA, 16 B per lane, dest = wave-uniform base + lane*16
__device__ __forceinline__ void gload_lds16(const u16* g, u16* l) {
    __builtin_amdgcn_global_load_lds(
        (const __attribute__((address_space(1))) unsigned int*)g,
        (__attribute__((address_space(3))) unsigned int*)l, 16, 0, 0);
}
// swizzled LDS index for a 32-u16-wide tile row: logical k-group g of row r
// stored at g ^ ((r>>1)&3)  -> 2-way bank aliasing only (free) for b128 reads
__device__ __forceinline__ int sw_idx(int r, int g) {
    return r * 32 + ((g ^ ((r >> 1) & 3)) * 8);
}

// ---- dtype detect: if buffer is fp32, even-index u16s are mantissa-low garbage ----
__global__ void detect_kernel(const void* x, int* flag)
{
    __shared__ int bad;
    if (threadIdx.x == 0) bad = 0;
    __syncthreads();
    const u16* p = (const u16*)x;
    int local = 0;
    for (int i = threadIdx.x; i < 2048; i += 256) {
        const float v = bf2f(p[2 * i]);
        if (!(fabsf(v) < 1e4f)) local = 1;
    }
    if (local) atomicOr(&bad, 1);
    __syncthreads();
    if (threadIdx.x == 0) *flag = bad;       // 1 => inputs are fp32
}

// ---- fused weight transpose: 4 jobs in one launch, 64x64 LDS tiles ----
__global__ __launch_bounds__(256) void transpose_all_kernel(
    const void* __restrict__ W_in, const void* __restrict__ W_xp,
    const void* __restrict__ W_dt, const void* __restrict__ W_out,
    u16* __restrict__ WtIn, u16* __restrict__ WtXp,
    u16* __restrict__ WtDt, u16* __restrict__ WtOut,
    const int* __restrict__ flagp)
{
    const bool f32 = (*flagp != 0);
    int bid = blockIdx.x;
    const void* src; u16* dst; int K, N, bx, by;
    if (bid < 576)      { src = W_in;  dst = WtIn;  K = 768;  N = 3072; bx = bid % 48; by = bid / 48; }
    else if (bid < 624) { bid -= 576; src = W_xp;  dst = WtXp;  K = 1536; N = 128;  bx = bid % 2;  by = bid / 2; }
    else if (bid < 672) { bid -= 624; src = W_dt;  dst = WtDt;  K = 96;   N = 1536; bx = bid % 24; by = bid / 24; }
    else                { bid -= 672; src = W_out; dst = WtOut; K = 1536; N = 768;  bx = bid % 12; by = bid / 12; }
    __shared__ u16 tile[64][72];
    const int t  = threadIdx.x;
    const int n0 = bx * 64, k0 = by * 64;
    {
        const int r = t >> 2, c = (t & 3) * 16;     // tile-local (k, n)
        const int k = k0 + r;
        if (k < K) {
            #pragma unroll
            for (int i = 0; i < 16; ++i)
                tile[r][c + i] = f2bf(ldx(src, (size_t)k * N + n0 + c + i, f32));
        }
    }
    __syncthreads();
    {
        const int nl = t >> 2, kl = (t & 3) * 16;   // tile-local (n, k)
        const int n = n0 + nl;
        #pragma unroll
        for (int i = 0; i < 16; ++i) {
            const int k = k0 + kl + i;
            if (k < K) dst[(size_t)n * K + k] = tile[kl + i][nl];
        }
    }
}

// ---------------- LayerNorm: x (T,768) -> xn (T,768) bf16 ----------------
__global__ __launch_bounds__(256) void ln_kernel(const void* __restrict__ x,
    const void* __restrict__ g, const void* __restrict__ b, u16* __restrict__ xn,
    const int* __restrict__ flagp)
{
    const bool f32 = (*flagp != 0);
    const int tok = blockIdx.x;
    const int tid = threadIdx.x;
    const size_t base = (size_t)tok * D_MODEL;
    float v[3];
    v[0] = ldx(x, base + tid, f32);
    v[1] = ldx(x, base + tid + 256, f32);
    v[2] = ldx(x, base + tid + 512, f32);
    float s = v[0] + v[1] + v[2];
    float q = v[0]*v[0] + v[1]*v[1] + v[2]*v[2];
    #pragma unroll
    for (int o = 32; o > 0; o >>= 1) {
        s += __shfl_down(s, o, 64);
        q += __shfl_down(q, o, 64);
    }
    __shared__ float ss[4], qq[4];
    if ((tid & 63) == 0) { ss[tid >> 6] = s; qq[tid >> 6] = q; }
    __syncthreads();
    const float S = ss[0] + ss[1] + ss[2] + ss[3];
    const float Q = qq[0] + qq[1] + qq[2] + qq[3];
    const float mu  = S * (1.f / D_MODEL);
    const float var = Q * (1.f / D_MODEL) - mu * mu;
    const float rs  = rsqrtf(var + 1e-5f);
    u16* outr = xn + base;
    #pragma unroll
    for (int i = 0; i < 3; ++i) {
        const int c = tid + i * 256;
        outr[c] = f2bf((v[i] - mu) * rs * ldx(g, c, f32) + ldx(b, c, f32));
    }
}

// ------- MFMA GEMM 64x64 tile, BK=32, 4 waves; async-DMA staging, swizzled LDS -------
// 64 rows x 32 u16 per buffer = 4 wave-DMAs (each covers 16 rows).
// EPI 0: bf16 store. EPI 2: + res[idx] (flex), flex store. EPI 3: atomicAdd fp32 (split-K).
template<int EPI>
__global__ __launch_bounds__(256) void mfma_gemm(
    const u16* __restrict__ A, const u16* __restrict__ Bt,
    u16* __restrict__ C, void* __restrict__ Cout, const void* __restrict__ aux,
    float* __restrict__ Cf, const int* __restrict__ flagp,
    int Kslice, int lda, int ldbt, int ldc)
{
    const bool f32 = (*flagp != 0);
    __shared__ __align__(16) u16 As[64 * 32];
    __shared__ __align__(16) u16 Bs[64 * 32];
    const int tid  = threadIdx.x;
    const int wave = tid >> 6, lane = tid & 63;
    const int lrow = lane & 15, quad = lane >> 4;
    const int row0 = blockIdx.y * 64, col0 = blockIdx.x * 64;
    const int k0   = blockIdx.z * Kslice;
    // DMA staging: wave w covers tile rows w*16..w*16+15; lane -> (r, swizzled k-group)
    const int sr = wave * 16 + (lane >> 2);
    const int scg = (lane & 3) ^ ((sr >> 1) & 3);   // logical k-group this lane fetches
    f32x4 acc[4] = {{0.f,0.f,0.f,0.f},{0.f,0.f,0.f,0.f},{0.f,0.f,0.f,0.f},{0.f,0.f,0.f,0.f}};
    for (int kt = k0; kt < k0 + Kslice; kt += 32) {
        gload_lds16(A  + (size_t)(row0 + sr) * lda  + kt + scg * 8, &As[wave * 512]);
        gload_lds16(Bt + (size_t)(col0 + sr) * ldbt + kt + scg * 8, &Bs[wave * 512]);
        __syncthreads();
        const bf16x8 af = *(const bf16x8*)(&As[sw_idx(wave * 16 + lrow, quad)]);
        #pragma unroll
        for (int t = 0; t < 4; ++t) {
            const bf16x8 bf_ = *(const bf16x8*)(&Bs[sw_idx(t * 16 + lrow, quad)]);
            acc[t] = __builtin_amdgcn_mfma_f32_16x16x32_bf16(af, bf_, acc[t], 0, 0, 0);
        }
        __syncthreads();
    }
    #pragma unroll
    for (int t = 0; t < 4; ++t) {
        #pragma unroll
        for (int r = 0; r < 4; ++r) {
            const int row = row0 + wave * 16 + quad * 4 + r;   // C/D: row=quad*4+reg
            const int col = col0 + t * 16 + lrow;              //      col=lane&15
            const size_t idx = (size_t)row * ldc + col;
            float vv = acc[t][r];
            if (EPI == 2) {
                vv += ldx(aux, idx, f32);
                if (f32) ((float*)Cout)[idx] = vv;
                else     ((u16*)Cout)[idx]   = f2bf(vv);
            } else if (EPI == 3) {
                atomicAdd(&Cf[idx], vv);
            } else {
                C[idx] = f2bf(vv);
            }
        }
    }
}

// ------- MFMA GEMM 128x128 tile, BK=32, 4 waves (2x2); async-DMA staging, swizzled -------
// FIX R11: 128 rows x 32 u16 per buffer = 8 wave-DMAs (q=0..1, region wave*2+q),
// NOT 16 (q=0..3 wrote rows up to 255 -> LDS overflow -> garbage).
// EPI 0: bf16 store. EPI 1: softplus(acc + bias[col]) bf16 store.
template<int EPI>
__global__ __launch_bounds__(256) void mfma_gemm128(
    const u16* __restrict__ A, const u16* __restrict__ Bt,
    u16* __restrict__ C, const void* __restrict__ aux,
    const int* __restrict__ flagp,
    int K, int lda, int ldbt, int ldc)
{
    const bool f32 = (*flagp != 0);
    __shared__ __align__(16) u16 As[128 * 32];
    __shared__ __align__(16) u16 Bs[128 * 32];
    const int tid  = threadIdx.x;
    const int wave = tid >> 6, lane = tid & 63;
    const int lrow = lane & 15, quad = lane >> 4;
    const int wy = wave >> 1, wx = wave & 1;
    const int row0 = blockIdx.y * 128, col0 = blockIdx.x * 128;
    f32x4 acc[4][4];
    #pragma unroll
    for (int i = 0; i < 4; ++i)
        #pragma unroll
        for (int j = 0; j < 4; ++j) acc[i][j] = (f32x4){0.f,0.f,0.f,0.f};
    for (int kt = 0; kt < K; kt += 32) {
        #pragma unroll
        for (int q = 0; q < 2; ++q) {
            const int reg = wave * 2 + q;                      // region 0..7
            const int r   = reg * 16 + (lane >> 2);            // tile row 0..127
            const int scg = (lane & 3) ^ ((r >> 1) & 3);       // logical k-group
            gload_lds16(A  + (size_t)(row0 + r) * lda  + kt + scg * 8, &As[reg * 512]);
            gload_lds16(Bt + (size_t)(col0 + r) * ldbt + kt + scg * 8, &Bs[reg * 512]);
        }
        __syncthreads();
        bf16x8 af[4], bf_[4];
        #pragma unroll
        for (int i = 0; i < 4; ++i)
            af[i] = *(const bf16x8*)(&As[sw_idx(wy * 64 + i * 16 + lrow, quad)]);
        #pragma unroll
        for (int j = 0; j < 4; ++j)
            bf_[j] = *(const bf16x8*)(&Bs[sw_idx(wx * 64 + j * 16 + lrow, quad)]);
        #pragma unroll
        for (int i = 0; i < 4; ++i)
            #pragma unroll
            for (int j = 0; j < 4; ++j)
                acc[i][j] = __builtin_amdgcn_mfma_f32_16x16x32_bf16(af[i], bf_[j], acc[i][j], 0, 0, 0);
        __syncthreads();
    }
    #pragma unroll
    for (int i = 0; i < 4; ++i) {
        #pragma unroll
        for (int j = 0; j < 4; ++j) {
            #pragma unroll
            for (int r = 0; r < 4; ++r) {
                const int row = row0 + wy * 64 + i * 16 + quad * 4 + r;
                const int col = col0 + wx * 64 + j * 16 + lrow;
                const size_t idx = (size_t)row * ldc + col;
                float vv = acc[i][j][r];
                if (EPI == 1) {
                    vv += ldx(aux, col, f32);
                    vv = (vv > 20.f) ? vv : log1pf(__expf(vv));
                }
                C[idx] = f2bf(vv);
            }
        }
    }
}

// -------- split-K finalize: xdbl = bf16(xdblF) --------
__global__ __launch_bounds__(256) void convert_kernel(const float* __restrict__ src,
                                                      u16* __restrict__ dst, int n)
{
    const int i = blockIdx.x * 256 + threadIdx.x;
    if (i < n) dst[i] = f2bf(src[i]);
}

// ---- causal depthwise conv (width 4, left-pad 3) + SiLU: uv[:, :1536] -> us ----
__global__ __launch_bounds__(256) void conv_silu_kernel(
    const u16* __restrict__ uv, const void* __restrict__ cw, const void* __restrict__ cb,
    u16* __restrict__ us, const int* __restrict__ flagp)
{
    const bool f32 = (*flagp != 0);
    const int idx = blockIdx.x * 256 + threadIdx.x;
    const int d   = idx % D_INNER;
    const int tok = idx / D_INNER;
    const int l   = tok & (LL - 1);
    float acc = ldx(cb, d, f32);
    #pragma unroll
    for (int j = 0; j < 4; ++j) {
        const int li = l - 3 + j;
        if (li >= 0)
            acc += bf2f(uv[(size_t)(tok - 3 + j) * (2*D_INNER) + d]) * ldx(cw, d * 4 + j, f32);
    }
    us[idx] = f2bf(acc / (1.f + __expf(-acc)));
}

// ----- scan pass 1: per-chunk local scan -> carries; one thread owns a full d -----
// a_j = a_1^(j+1) when A2[j] = (j+1)*A2[0] (Mamba A-init) -> 1 exp2 + 15 muls per t.
__global__ __launch_bounds__(256) void scan1_kernel(
    const u16* __restrict__ delta, const u16* __restrict__ us,
    const u16* __restrict__ xdbl, const void* __restrict__ log_A,
    float* __restrict__ carryA, float* __restrict__ carryH,
    const int* __restrict__ flagp)
{
    const bool f32 = (*flagp != 0);
    const int d = blockIdx.x * 256 + threadIdx.x;
    const int c = blockIdx.y, b = blockIdx.z;
    float A2[16], h[16];
    #pragma unroll
    for (int j = 0; j < 16; ++j) {
        A2[j] = -__expf(ldx(log_A, d * D_STATE + j, f32)) * LOG2E;
        h[j] = 0.f;
    }
    bool pw = true;
    #pragma unroll
    for (int j = 1; j < 16; ++j)
        pw = pw && (fabsf(A2[j] - (j + 1) * A2[0]) <= 0.02f * (j + 1) * fabsf(A2[0]));
    float sdl = 0.f;
    size_t tok = (size_t)b * LL + c * CL;
    if (pw) {
        #pragma unroll 2
        for (int t = 0; t < CL; ++t, ++tok) {
            const float dl = bf2f(delta[tok * D_INNER + d]);
            const float ul = bf2f(us[tok * D_INNER + d]);
            const uint4 B0 = *(const uint4*)(xdbl + tok * 128 + DT_RANK);
            const uint4 B1 = *(const uint4*)(xdbl + tok * 128 + DT_RANK + 8);
            const float dlul = dl * ul;
            sdl += dl;
            const unsigned int bw[8] = {B0.x,B0.y,B0.z,B0.w,B1.x,B1.y,B1.z,B1.w};
            const float a1 = exp2f(dl * A2[0]);
            float aj = 1.f;
            #pragma unroll
            for (int j = 0; j < 16; ++j) {
                aj *= a1;
                const float Bn = (j & 1) ? bfu_hi(bw[j >> 1]) : bfu_lo(bw[j >> 1]);
                h[j] = aj * h[j] + dlul * Bn;
            }
        }
    } else {
        #pragma unroll 2
        for (int t = 0; t < CL; ++t, ++tok) {
            const float dl = bf2f(delta[tok * D_INNER + d]);
            const float ul = bf2f(us[tok * D_INNER + d]);
            const uint4 B0 = *(const uint4*)(xdbl + tok * 128 + DT_RANK);
            const uint4 B1 = *(const uint4*)(xdbl + tok * 128 + DT_RANK + 8);
            const float dlul = dl * ul;
            sdl += dl;
            const unsigned int bw[8] = {B0.x,B0.y,B0.z,B0.w,B1.x,B1.y,B1.z,B1.w};
            #pragma unroll
            for (int j = 0; j < 16; ++j) {
                const float Bn = (j & 1) ? bfu_hi(bw[j >> 1]) : bfu_lo(bw[j >> 1]);
                h[j] = exp2f(dl * A2[j]) * h[j] + dlul * Bn;
            }
        }
    }
    const size_t ci = (((size_t)b * NC + c) * D_INNER + d) * D_STATE;
    #pragma unroll
    for (int q = 0; q < 4; ++q) {
        *(float4*)(carryA + ci + 4*q) = (float4){
            exp2f(A2[4*q+0]*sdl), exp2f(A2[4*q+1]*sdl),
            exp2f(A2[4*q+2]*sdl), exp2f(A2[4*q+3]*sdl)};
        *(float4*)(carryH + ci + 4*q) = (float4){h[4*q+0], h[4*q+1], h[4*q+2], h[4*q+3]};
    }
}

// -------- scan pass 2: exclusive scan over chunk carries, in place on carryH --------
__global__ __launch_bounds__(256) void scan2_kernel(
    const float* __restrict__ carryA, float* __restrict__ carryH)
{
    const int gid = blockIdx.x * 256 + threadIdx.x;
    const int b   = gid / (D_INNER * D_STATE);
    const int dn  = gid % (D_INNER * D_STATE);
    float hrun = 0.f;
    #pragma unroll
    for (int c = 0; c < NC; ++c) {
        const size_t ci = ((size_t)(b * NC + c) * D_INNER * D_STATE) + dn;
        const float a = carryA[ci], hh = carryH[ci];
        carryH[ci] = hrun;
        hrun = a * hrun + hh;
    }
}

// ------ scan pass 3: re-run chunk seeded with carry; emit gated y; full-d threads ------
__global__ __launch_bounds__(256) void scan3_kernel(
    const u16* __restrict__ delta, const u16* __restrict__ us,
    const u16* __restrict__ xdbl, u16* __restrict__ uv,
    const void* __restrict__ log_A, const void* __restrict__ D_param,
    const float* __restrict__ carryH, const int* __restrict__ flagp)
{
    const bool f32 = (*flagp != 0);
    const int d = blockIdx.x * 256 + threadIdx.x;
    const int c = blockIdx.y, b = blockIdx.z;
    const float Dd = ldx(D_param, d, f32);
    float A2[16], h[16];
    const size_t ci = (((size_t)b * NC + c) * D_INNER + d) * D_STATE;
    #pragma unroll
    for (int j = 0; j < 16; ++j)
        A2[j] = -__expf(ldx(log_A, d * D_STATE + j, f32)) * LOG2E;
    bool pw = true;
    #pragma unroll
    for (int j = 1; j < 16; ++j)
        pw = pw && (fabsf(A2[j] - (j + 1) * A2[0]) <= 0.02f * (j + 1) * fabsf(A2[0]));
    #pragma unroll
    for (int q = 0; q < 4; ++q) {
        const float4 hq = *(const float4*)(carryH + ci + 4*q);
        h[4*q+0] = hq.x; h[4*q+1] = hq.y; h[4*q+2] = hq.z; h[4*q+3] = hq.w;
    }
    size_t tok = (size_t)b * LL + c * CL;
    if (pw) {
        #pragma unroll 2
        for (int t = 0; t < CL; ++t, ++tok) {
            const float dl = bf2f(delta[tok * D_INNER + d]);
            const float ul = bf2f(us[tok * D_INNER + d]);
            const uint4 B0 = *(const uint4*)(xdbl + tok * 128 + DT_RANK);
            const uint4 B1 = *(const uint4*)(xdbl + tok * 128 + DT_RANK + 8);
            const uint4 C0 = *(const uint4*)(xdbl + tok * 128 + DT_RANK + D_STATE);
            const uint4 C1 = *(const uint4*)(xdbl + tok * 128 + DT_RANK + D_STATE + 8);
            const float dlul = dl * ul;
            const unsigned int bw[8] = {B0.x,B0.y,B0.z,B0.w,B1.x,B1.y,B1.z,B1.w};
            const unsigned int cw_[8] = {C0.x,C0.y,C0.z,C0.w,C1.x,C1.y,C1.z,C1.w};
            const float a1 = exp2f(dl * A2[0]);
            float aj = 1.f, p = 0.f;
            #pragma unroll
            for (int j = 0; j < 16; ++j) {
                aj *= a1;
                const float Bn = (j & 1) ? bfu_hi(bw[j >> 1]) : bfu_lo(bw[j >> 1]);
                const float Cn = (j & 1) ? bfu_hi(cw_[j >> 1]) : bfu_lo(cw_[j >> 1]);
                h[j] = aj * h[j] + dlul * Bn;
                p += h[j] * Cn;
            }
            const float vv = bf2f(uv[tok * (2*D_INNER) + D_INNER + d]);
            uv[tok * (2*D_INNER) + d] = f2bf((p + ul * Dd) * (vv / (1.f + __expf(-vv))));
        }
    } else {
        #pragma unroll 2
        for (int t = 0; t < CL; ++t, ++tok) {
            const float dl = bf2f(delta[tok * D_INNER + d]);
            const float ul = bf2f(us[tok * D_INNER + d]);
            const uint4 B0 = *(const uint4*)(xdbl + tok * 128 + DT_RANK);
            const uint4 B1 = *(const uint4*)(xdbl + tok * 128 + DT_RANK + 8);
            const uint4 C0 = *(const uint4*)(xdbl + tok * 128 + DT_RANK + D_STATE);
            const uint4 C1 = *(const uint4*)(xdbl + tok * 128 + DT_RANK + D_STATE + 8);
            const float dlul = dl * ul;
            const unsigned int bw[8] = {B0.x,B0.y,B0.z,B0.w,B1.x,B1.y,B1.z,B1.w};
            const unsigned int cw_[8] = {C0.x,C0.y,C0.z,C0.w,C1.x,C1.y,C1.z,C1.w};
            float p = 0.f;
            #pragma unroll
            for (int j = 0; j < 16; ++j) {
                const float Bn = (j & 1) ? bfu_hi(bw[j >> 1]) : bfu_lo(bw[j >> 1]);
                const float Cn = (j & 1) ? bfu_hi(cw_[j >> 1]) : bfu_lo(cw_[j >> 1]);
                h[j] = exp2f(dl * A2[j]) * h[j] + dlul * Bn;
                p += h[j] * Cn;
            }
            const float vv = bf2f(uv[tok * (2*D_INNER) + D_INNER + d]);
            uv[tok * (2*D_INNER) + d] = f2bf((p + ul * Dd) * (vv / (1.f + __expf(-vv))));
        }
    }
}

extern "C" void kernel_launch(void* const* d_in, const int* in_sizes, int n_in,
                              void* d_out, int out_size, void* d_ws, size_t ws_size,
                              hipStream_t stream)
{
    const void* x      = d_in[0];
    const void* ln_g   = d_in[1];
    const void* ln_b   = d_in[2];
    const void* W_in   = d_in[3];
    const void* conv_w = d_in[4];
    const void* conv_b = d_in[5];
    const void* W_xp   = d_in[6];
    const void* W_dt   = d_in[7];
    const void* b_dt   = d_in[8];
    const void* log_A  = d_in[9];
    const void* D_par  = d_in[10];
    const void* W_out  = d_in[11];

    // workspace (~93 MB): flag | xn | uv | us | xdbl | delta | carryH | carryA |
    //                     WtIn | WtXp | WtDt | WtOut | xdblF
    int* flag  = (int*)d_ws;
    u16* ws    = (u16*)((char*)d_ws + 512);
    u16* xn    = ws;
    u16* uv    = xn + (size_t)TT * D_MODEL;
    u16* us    = uv + (size_t)TT * 2 * D_INNER;
    u16* xdbl  = us + (size_t)TT * D_INNER;
    u16* delta = xdbl + (size_t)TT * 128;
    float* carryH = (float*)(delta + (size_t)TT * D_INNER);
    float* carryA = carryH + (size_t)BB * NC * D_INNER * D_STATE;
    u16* WtIn  = (u16*)(carryA + (size_t)BB * NC * D_INNER * D_STATE);
    u16* WtXp  = WtIn  + (size_t)2 * D_INNER * D_MODEL;
    u16* WtDt  = WtXp  + (size_t)(DT_RANK + 2 * D_STATE) * D_INNER;
    u16* WtOut = WtDt  + (size_t)D_INNER * DT_RANK;
    float* xdblF = (float*)(WtOut + (size_t)D_MODEL * D_INNER);

    detect_kernel<<<1, 256, 0, stream>>>(x, flag);
    transpose_all_kernel<<<960, 256, 0, stream>>>(
        W_in, W_xp, W_dt, W_out, WtIn, WtXp, WtDt, WtOut, flag);
    hipMemsetAsync(xdblF, 0, (size_t)TT * 128 * sizeof(float), stream);

    ln_kernel<<<TT, 256, 0, stream>>>(x, ln_g, ln_b, xn, flag);
    // uv = xn @ W_in  (4096x3072, K=768)  [128x128, 768 blocks]
    mfma_gemm128<0><<<dim3(2 * D_INNER / 128, TT / 128), 256, 0, stream>>>(
        xn, WtIn, uv, nullptr, flag, D_MODEL, D_MODEL, D_MODEL, 2 * D_INNER);
    // us = silu(causal_conv(uv[:, :1536]))
    conv_silu_kernel<<<(TT * D_INNER) / 256, 256, 0, stream>>>(uv, conv_w, conv_b, us, flag);
    // xdbl = us @ W_xproj  (4096x128, K=1536)  [64x64, split-K x4]
    mfma_gemm<3><<<dim3(2, TT / 64, SKK), 256, 0, stream>>>(
        us, WtXp, nullptr, nullptr, nullptr, xdblF, flag,
        D_INNER / SKK, D_INNER, D_INNER, 128);
    convert_kernel<<<(TT * 128 + 255) / 256, 256, 0, stream>>>(xdblF, xdbl, TT * 128);
    // delta = softplus(xdbl[:, :96] @ W_dt + b_dt)  (4096x1536, K=96)  [128x128]
    mfma_gemm128<1><<<dim3(D_INNER / 128, TT / 128), 256, 0, stream>>>(
        xdbl, WtDt, delta, b_dt, flag, DT_RANK, 128, DT_RANK, D_INNER);
    // chunked selective scan (full-d threads: 768 blocks per pass)
    scan1_kernel<<<dim3(D_INNER / 256, NC, BB), 256, 0, stream>>>(
        delta, us, xdbl, log_A, carryA, carryH, flag);
    scan2_kernel<<<(BB * D_INNER * D_STATE) / 256, 256, 0, stream>>>(carryA, carryH);
    scan3_kernel<<<dim3(D_INNER / 256, NC, BB), 256, 0, stream>>>(
        delta, us, xdbl, uv, log_A, D_par, carryH, flag);
    // out = y @ W_out + x  (4096x768, K=1536)  [64x64, 768 blocks]
    mfma_gemm<2><<<dim3(D_MODEL / 64, TT / 64, 1), 256, 0, stream>>>(
        uv, WtOut, nullptr, d_out, x, nullptr, flag,
        D_INNER, 2 * D_INNER, D_INNER, D_MODEL);
}

// Round 13
// 391.344 us; speedup vs baseline: 1.0144x; 1.0144x over previous
//
#include <hip/hip_runtime.h>

#define D_MODEL 768
#define D_INNER 1536
#define D_STATE 16
#define DT_RANK 96
#define BB 2
#define LL 2048
#define TT (BB*LL)          // 4096 tokens
#define NC 64               // chunks per sequence
#define CL 32               // chunk length
#define SKK 4               // split-K factor for xdbl GEMM
#define LOG2E 1.44269504f

typedef unsigned short u16;
typedef short bf16x8 __attribute__((ext_vector_type(8)));
typedef unsigned short u16x8 __attribute__((ext_vector_type(8)));
typedef float f32x4  __attribute__((ext_vector_type(4)));

__device__ __forceinline__ float bf2f(u16 u) {
    union { unsigned int i; float f; } c; c.i = ((unsigned int)u) << 16; return c.f;
}
__device__ __forceinline__ u16 f2bf(float f) {
    union { float f; unsigned int i; } c; c.f = f;
    unsigned int x = c.i;
    return (u16)((x + 0x7fffu + ((x >> 16) & 1u)) >> 16);   // RNE
}
__device__ __forceinline__ float bfu_lo(unsigned int u) {
    union { unsigned int i; float f; } c; c.i = u << 16; return c.f;
}
__device__ __forceinline__ float bfu_hi(unsigned int u) {
    union { unsigned int i; float f; } c; c.i = u & 0xFFFF0000u; return c.f;
}
__device__ __forceinline__ float ldx(const void* p, size_t i, bool f32) {
    return f32 ? ((const float*)p)[i] : bf2f(((const u16*)p)[i]);
}

// ---- dtype detect: if buffer is fp32, even-index u16s are mantissa-low garbage ----
__global__ void detect_kernel(const void* x, int* flag)
{
    __shared__ int bad;
    if (threadIdx.x == 0) bad = 0;
    __syncthreads();
    const u16* p = (const u16*)x;
    int local = 0;
    for (int i = threadIdx.x; i < 2048; i += 256) {
        const float v = bf2f(p[2 * i]);
        if (!(fabsf(v) < 1e4f)) local = 1;
    }
    if (local) atomicOr(&bad, 1);
    __syncthreads();
    if (threadIdx.x == 0) *flag = bad;       // 1 => inputs are fp32
}

// ---- fused weight transpose: 4 jobs in one launch, 64x64 LDS tiles ----
__global__ __launch_bounds__(256) void transpose_all_kernel(
    const void* __restrict__ W_in, const void* __restrict__ W_xp,
    const void* __restrict__ W_dt, const void* __restrict__ W_out,
    u16* __restrict__ WtIn, u16* __restrict__ WtXp,
    u16* __restrict__ WtDt, u16* __restrict__ WtOut,
    const int* __restrict__ flagp)
{
    const bool f32 = (*flagp != 0);
    int bid = blockIdx.x;
    const void* src; u16* dst; int K, N, bx, by;
    if (bid < 576)      { src = W_in;  dst = WtIn;  K = 768;  N = 3072; bx = bid % 48; by = bid / 48; }
    else if (bid < 624) { bid -= 576; src = W_xp;  dst = WtXp;  K = 1536; N = 128;  bx = bid % 2;  by = bid / 2; }
    else if (bid < 672) { bid -= 624; src = W_dt;  dst = WtDt;  K = 96;   N = 1536; bx = bid % 24; by = bid / 24; }
    else                { bid -= 672; src = W_out; dst = WtOut; K = 1536; N = 768;  bx = bid % 12; by = bid / 12; }
    __shared__ u16 tile[64][72];
    const int t  = threadIdx.x;
    const int n0 = bx * 64, k0 = by * 64;
    {
        const int r = t >> 2, c = (t & 3) * 16;     // tile-local (k, n)
        const int k = k0 + r;
        if (k < K) {
            #pragma unroll
            for (int i = 0; i < 16; ++i)
                tile[r][c + i] = f2bf(ldx(src, (size_t)k * N + n0 + c + i, f32));
        }
    }
    __syncthreads();
    {
        const int nl = t >> 2, kl = (t & 3) * 16;   // tile-local (n, k)
        const int n = n0 + nl;
        #pragma unroll
        for (int i = 0; i < 16; ++i) {
            const int k = k0 + kl + i;
            if (k < K) dst[(size_t)n * K + k] = tile[kl + i][nl];
        }
    }
}

// ---------------- LayerNorm: x (T,768) -> xn (T,768) bf16 ----------------
__global__ __launch_bounds__(256) void ln_kernel(const void* __restrict__ x,
    const void* __restrict__ g, const void* __restrict__ b, u16* __restrict__ xn,
    const int* __restrict__ flagp)
{
    const bool f32 = (*flagp != 0);
    const int tok = blockIdx.x;
    const int tid = threadIdx.x;
    const size_t base = (size_t)tok * D_MODEL;
    float v[3];
    v[0] = ldx(x, base + tid, f32);
    v[1] = ldx(x, base + tid + 256, f32);
    v[2] = ldx(x, base + tid + 512, f32);
    float s = v[0] + v[1] + v[2];
    float q = v[0]*v[0] + v[1]*v[1] + v[2]*v[2];
    #pragma unroll
    for (int o = 32; o > 0; o >>= 1) {
        s += __shfl_down(s, o, 64);
        q += __shfl_down(q, o, 64);
    }
    __shared__ float ss[4], qq[4];
    if ((tid & 63) == 0) { ss[tid >> 6] = s; qq[tid >> 6] = q; }
    __syncthreads();
    const float S = ss[0] + ss[1] + ss[2] + ss[3];
    const float Q = qq[0] + qq[1] + qq[2] + qq[3];
    const float mu  = S * (1.f / D_MODEL);
    const float var = Q * (1.f / D_MODEL) - mu * mu;
    const float rs  = rsqrtf(var + 1e-5f);
    u16* outr = xn + base;
    #pragma unroll
    for (int i = 0; i < 3; ++i) {
        const int c = tid + i * 256;
        outr[c] = f2bf((v[i] - mu) * rs * ldx(g, c, f32) + ldx(b, c, f32));
    }
}

// ------- MFMA GEMM 64x64 tile, BK=32, 4 waves; A (M,K) bf16, Bt (N,K) bf16 -------
// ds_write staging (R8-proven): u16x8 per thread per buffer into padded SA=40 LDS.
// NOTE (R12 lesson): global_load_lds DMA regressed 3x here — our per-lane addresses
// span 16 rows -> 16 scattered 64B transactions per DMA. Needs lane-contiguous
// global layout to win; ds_write staging is the right tool for this layout.
// EPI 0: bf16 store. EPI 2: + res[idx] (flex), flex store. EPI 3: atomicAdd fp32 (split-K).
#define SA 40
template<int EPI>
__global__ __launch_bounds__(256) void mfma_gemm(
    const u16* __restrict__ A, const u16* __restrict__ Bt,
    u16* __restrict__ C, void* __restrict__ Cout, const void* __restrict__ aux,
    float* __restrict__ Cf, const int* __restrict__ flagp,
    int Kslice, int lda, int ldbt, int ldc)
{
    const bool f32 = (*flagp != 0);
    __shared__ u16 As[64 * SA];
    __shared__ u16 Bs[64 * SA];
    const int tid  = threadIdx.x;
    const int wave = tid >> 6, lane = tid & 63;
    const int lrow = lane & 15, quad = lane >> 4;
    const int row0 = blockIdx.y * 64, col0 = blockIdx.x * 64;
    const int k0   = blockIdx.z * Kslice;
    const int sr = tid >> 2, sk = (tid & 3) * 8;    // staging: (row, k-chunk)
    f32x4 acc[4] = {{0.f,0.f,0.f,0.f},{0.f,0.f,0.f,0.f},{0.f,0.f,0.f,0.f},{0.f,0.f,0.f,0.f}};
    for (int kt = k0; kt < k0 + Kslice; kt += 32) {
        *(u16x8*)(&As[sr * SA + sk]) = *(const u16x8*)(A  + (size_t)(row0 + sr) * lda  + kt + sk);
        *(u16x8*)(&Bs[sr * SA + sk]) = *(const u16x8*)(Bt + (size_t)(col0 + sr) * ldbt + kt + sk);
        __syncthreads();
        const bf16x8 af = *(const bf16x8*)(&As[(wave * 16 + lrow) * SA + quad * 8]);
        #pragma unroll
        for (int t = 0; t < 4; ++t) {
            const bf16x8 bf_ = *(const bf16x8*)(&Bs[(t * 16 + lrow) * SA + quad * 8]);
            acc[t] = __builtin_amdgcn_mfma_f32_16x16x32_bf16(af, bf_, acc[t], 0, 0, 0);
        }
        __syncthreads();
    }
    #pragma unroll
    for (int t = 0; t < 4; ++t) {
        #pragma unroll
        for (int r = 0; r < 4; ++r) {
            const int row = row0 + wave * 16 + quad * 4 + r;   // C/D: row=quad*4+reg
            const int col = col0 + t * 16 + lrow;              //      col=lane&15
            const size_t idx = (size_t)row * ldc + col;
            float vv = acc[t][r];
            if (EPI == 2) {
                vv += ldx(aux, idx, f32);
                if (f32) ((float*)Cout)[idx] = vv;
                else     ((u16*)Cout)[idx]   = f2bf(vv);
            } else if (EPI == 3) {
                atomicAdd(&Cf[idx], vv);
            } else {
                C[idx] = f2bf(vv);
            }
        }
    }
}

// ------- MFMA GEMM 128x128 tile, BK=32, 4 waves (2x2); ds_write staging (R8) -------
// EPI 0: bf16 store. EPI 1: softplus(acc + bias[col]) bf16 store.
template<int EPI>
__global__ __launch_bounds__(256) void mfma_gemm128(
    const u16* __restrict__ A, const u16* __restrict__ Bt,
    u16* __restrict__ C, const void* __restrict__ aux,
    const int* __restrict__ flagp,
    int K, int lda, int ldbt, int ldc)
{
    const bool f32 = (*flagp != 0);
    __shared__ u16 As[128 * SA];
    __shared__ u16 Bs[128 * SA];
    const int tid  = threadIdx.x;
    const int wave = tid >> 6, lane = tid & 63;
    const int lrow = lane & 15, quad = lane >> 4;
    const int wy = wave >> 1, wx = wave & 1;
    const int row0 = blockIdx.y * 128, col0 = blockIdx.x * 128;
    const int sr = tid >> 1, sk = (tid & 1) * 16;   // staging: (row, k-half)
    f32x4 acc[4][4];
    #pragma unroll
    for (int i = 0; i < 4; ++i)
        #pragma unroll
        for (int j = 0; j < 4; ++j) acc[i][j] = (f32x4){0.f,0.f,0.f,0.f};
    for (int kt = 0; kt < K; kt += 32) {
        *(u16x8*)(&As[sr * SA + sk])     = *(const u16x8*)(A  + (size_t)(row0 + sr) * lda  + kt + sk);
        *(u16x8*)(&As[sr * SA + sk + 8]) = *(const u16x8*)(A  + (size_t)(row0 + sr) * lda  + kt + sk + 8);
        *(u16x8*)(&Bs[sr * SA + sk])     = *(const u16x8*)(Bt + (size_t)(col0 + sr) * ldbt + kt + sk);
        *(u16x8*)(&Bs[sr * SA + sk + 8]) = *(const u16x8*)(Bt + (size_t)(col0 + sr) * ldbt + kt + sk + 8);
        __syncthreads();
        bf16x8 af[4], bf_[4];
        #pragma unroll
        for (int i = 0; i < 4; ++i)
            af[i] = *(const bf16x8*)(&As[(wy * 64 + i * 16 + lrow) * SA + quad * 8]);
        #pragma unroll
        for (int j = 0; j < 4; ++j)
            bf_[j] = *(const bf16x8*)(&Bs[(wx * 64 + j * 16 + lrow) * SA + quad * 8]);
        #pragma unroll
        for (int i = 0; i < 4; ++i)
            #pragma unroll
            for (int j = 0; j < 4; ++j)
                acc[i][j] = __builtin_amdgcn_mfma_f32_16x16x32_bf16(af[i], bf_[j], acc[i][j], 0, 0, 0);
        __syncthreads();
    }
    #pragma unroll
    for (int i = 0; i < 4; ++i) {
        #pragma unroll
        for (int j = 0; j < 4; ++j) {
            #pragma unroll
            for (int r = 0; r < 4; ++r) {
                const int row = row0 + wy * 64 + i * 16 + quad * 4 + r;
                const int col = col0 + wx * 64 + j * 16 + lrow;
                const size_t idx = (size_t)row * ldc + col;
                float vv = acc[i][j][r];
                if (EPI == 1) {
                    vv += ldx(aux, col, f32);
                    vv = (vv > 20.f) ? vv : log1pf(__expf(vv));
                }
                C[idx] = f2bf(vv);
            }
        }
    }
}

// -------- split-K finalize: xdbl = bf16(xdblF) --------
__global__ __launch_bounds__(256) void convert_kernel(const float* __restrict__ src,
                                                      u16* __restrict__ dst, int n)
{
    const int i = blockIdx.x * 256 + threadIdx.x;
    if (i < n) dst[i] = f2bf(src[i]);
}

// ---- causal depthwise conv (width 4, left-pad 3) + SiLU: uv[:, :1536] -> us ----
__global__ __launch_bounds__(256) void conv_silu_kernel(
    const u16* __restrict__ uv, const void* __restrict__ cw, const void* __restrict__ cb,
    u16* __restrict__ us, const int* __restrict__ flagp)
{
    const bool f32 = (*flagp != 0);
    const int idx = blockIdx.x * 256 + threadIdx.x;
    const int d   = idx % D_INNER;
    const int tok = idx / D_INNER;
    const int l   = tok & (LL - 1);
    float acc = ldx(cb, d, f32);
    #pragma unroll
    for (int j = 0; j < 4; ++j) {
        const int li = l - 3 + j;
        if (li >= 0)
            acc += bf2f(uv[(size_t)(tok - 3 + j) * (2*D_INNER) + d]) * ldx(cw, d * 4 + j, f32);
    }
    us[idx] = f2bf(acc / (1.f + __expf(-acc)));
}

// ----- scan pass 1: per-chunk local scan -> carries; one thread owns a full d -----
// a_j = a_1^(j+1) when A2[j] = (j+1)*A2[0] (Mamba A-init) -> 1 exp2 + 15 muls per t.
__global__ __launch_bounds__(256) void scan1_kernel(
    const u16* __restrict__ delta, const u16* __restrict__ us,
    const u16* __restrict__ xdbl, const void* __restrict__ log_A,
    float* __restrict__ carryA, float* __restrict__ carryH,
    const int* __restrict__ flagp)
{
    const bool f32 = (*flagp != 0);
    const int d = blockIdx.x * 256 + threadIdx.x;
    const int c = blockIdx.y, b = blockIdx.z;
    float A2[16], h[16];
    #pragma unroll
    for (int j = 0; j < 16; ++j) {
        A2[j] = -__expf(ldx(log_A, d * D_STATE + j, f32)) * LOG2E;
        h[j] = 0.f;
    }
    bool pw = true;
    #pragma unroll
    for (int j = 1; j < 16; ++j)
        pw = pw && (fabsf(A2[j] - (j + 1) * A2[0]) <= 0.02f * (j + 1) * fabsf(A2[0]));
    float sdl = 0.f;
    size_t tok = (size_t)b * LL + c * CL;
    if (pw) {
        #pragma unroll 2
        for (int t = 0; t < CL; ++t, ++tok) {
            const float dl = bf2f(delta[tok * D_INNER + d]);
            const float ul = bf2f(us[tok * D_INNER + d]);
            const uint4 B0 = *(const uint4*)(xdbl + tok * 128 + DT_RANK);
            const uint4 B1 = *(const uint4*)(xdbl + tok * 128 + DT_RANK + 8);
            const float dlul = dl * ul;
            sdl += dl;
            const unsigned int bw[8] = {B0.x,B0.y,B0.z,B0.w,B1.x,B1.y,B1.z,B1.w};
            const float a1 = exp2f(dl * A2[0]);
            float aj = 1.f;
            #pragma unroll
            for (int j = 0; j < 16; ++j) {
                aj *= a1;
                const float Bn = (j & 1) ? bfu_hi(bw[j >> 1]) : bfu_lo(bw[j >> 1]);
                h[j] = aj * h[j] + dlul * Bn;
            }
        }
    } else {
        #pragma unroll 2
        for (int t = 0; t < CL; ++t, ++tok) {
            const float dl = bf2f(delta[tok * D_INNER + d]);
            const float ul = bf2f(us[tok * D_INNER + d]);
            const uint4 B0 = *(const uint4*)(xdbl + tok * 128 + DT_RANK);
            const uint4 B1 = *(const uint4*)(xdbl + tok * 128 + DT_RANK + 8);
            const float dlul = dl * ul;
            sdl += dl;
            const unsigned int bw[8] = {B0.x,B0.y,B0.z,B0.w,B1.x,B1.y,B1.z,B1.w};
            #pragma unroll
            for (int j = 0; j < 16; ++j) {
                const float Bn = (j & 1) ? bfu_hi(bw[j >> 1]) : bfu_lo(bw[j >> 1]);
                h[j] = exp2f(dl * A2[j]) * h[j] + dlul * Bn;
            }
        }
    }
    const size_t ci = (((size_t)b * NC + c) * D_INNER + d) * D_STATE;
    #pragma unroll
    for (int q = 0; q < 4; ++q) {
        *(float4*)(carryA + ci + 4*q) = (float4){
            exp2f(A2[4*q+0]*sdl), exp2f(A2[4*q+1]*sdl),
            exp2f(A2[4*q+2]*sdl), exp2f(A2[4*q+3]*sdl)};
        *(float4*)(carryH + ci + 4*q) = (float4){h[4*q+0], h[4*q+1], h[4*q+2], h[4*q+3]};
    }
}

// -------- scan pass 2: exclusive scan over chunk carries, in place on carryH --------
__global__ __launch_bounds__(256) void scan2_kernel(
    const float* __restrict__ carryA, float* __restrict__ carryH)
{
    const int gid = blockIdx.x * 256 + threadIdx.x;
    const int b   = gid / (D_INNER * D_STATE);
    const int dn  = gid % (D_INNER * D_STATE);
    float hrun = 0.f;
    #pragma unroll
    for (int c = 0; c < NC; ++c) {
        const size_t ci = ((size_t)(b * NC + c) * D_INNER * D_STATE) + dn;
        const float a = carryA[ci], hh = carryH[ci];
        carryH[ci] = hrun;
        hrun = a * hrun + hh;
    }
}

// ------ scan pass 3: re-run chunk seeded with carry; emit gated y; full-d threads ------
__global__ __launch_bounds__(256) void scan3_kernel(
    const u16* __restrict__ delta, const u16* __restrict__ us,
    const u16* __restrict__ xdbl, u16* __restrict__ uv,
    const void* __restrict__ log_A, const void* __restrict__ D_param,
    const float* __restrict__ carryH, const int* __restrict__ flagp)
{
    const bool f32 = (*flagp != 0);
    const int d = blockIdx.x * 256 + threadIdx.x;
    const int c = blockIdx.y, b = blockIdx.z;
    const float Dd = ldx(D_param, d, f32);
    float A2[16], h[16];
    const size_t ci = (((size_t)b * NC + c) * D_INNER + d) * D_STATE;
    #pragma unroll
    for (int j = 0; j < 16; ++j)
        A2[j] = -__expf(ldx(log_A, d * D_STATE + j, f32)) * LOG2E;
    bool pw = true;
    #pragma unroll
    for (int j = 1; j < 16; ++j)
        pw = pw && (fabsf(A2[j] - (j + 1) * A2[0]) <= 0.02f * (j + 1) * fabsf(A2[0]));
    #pragma unroll
    for (int q = 0; q < 4; ++q) {
        const float4 hq = *(const float4*)(carryH + ci + 4*q);
        h[4*q+0] = hq.x; h[4*q+1] = hq.y; h[4*q+2] = hq.z; h[4*q+3] = hq.w;
    }
    size_t tok = (size_t)b * LL + c * CL;
    if (pw) {
        #pragma unroll 2
        for (int t = 0; t < CL; ++t, ++tok) {
            const float dl = bf2f(delta[tok * D_INNER + d]);
            const float ul = bf2f(us[tok * D_INNER + d]);
            const uint4 B0 = *(const uint4*)(xdbl + tok * 128 + DT_RANK);
            const uint4 B1 = *(const uint4*)(xdbl + tok * 128 + DT_RANK + 8);
            const uint4 C0 = *(const uint4*)(xdbl + tok * 128 + DT_RANK + D_STATE);
            const uint4 C1 = *(const uint4*)(xdbl + tok * 128 + DT_RANK + D_STATE + 8);
            const float dlul = dl * ul;
            const unsigned int bw[8] = {B0.x,B0.y,B0.z,B0.w,B1.x,B1.y,B1.z,B1.w};
            const unsigned int cw_[8] = {C0.x,C0.y,C0.z,C0.w,C1.x,C1.y,C1.z,C1.w};
            const float a1 = exp2f(dl * A2[0]);
            float aj = 1.f, p = 0.f;
            #pragma unroll
            for (int j = 0; j < 16; ++j) {
                aj *= a1;
                const float Bn = (j & 1) ? bfu_hi(bw[j >> 1]) : bfu_lo(bw[j >> 1]);
                const float Cn = (j & 1) ? bfu_hi(cw_[j >> 1]) : bfu_lo(cw_[j >> 1]);
                h[j] = aj * h[j] + dlul * Bn;
                p += h[j] * Cn;
            }
            const float vv = bf2f(uv[tok * (2*D_INNER) + D_INNER + d]);
            uv[tok * (2*D_INNER) + d] = f2bf((p + ul * Dd) * (vv / (1.f + __expf(-vv))));
        }
    } else {
        #pragma unroll 2
        for (int t = 0; t < CL; ++t, ++tok) {
            const float dl = bf2f(delta[tok * D_INNER + d]);
            const float ul = bf2f(us[tok * D_INNER + d]);
            const uint4 B0 = *(const uint4*)(xdbl + tok * 128 + DT_RANK);
            const uint4 B1 = *(const uint4*)(xdbl + tok * 128 + DT_RANK + 8);
            const uint4 C0 = *(const uint4*)(xdbl + tok * 128 + DT_RANK + D_STATE);
            const uint4 C1 = *(const uint4*)(xdbl + tok * 128 + DT_RANK + D_STATE + 8);
            const float dlul = dl * ul;
            const unsigned int bw[8] = {B0.x,B0.y,B0.z,B0.w,B1.x,B1.y,B1.z,B1.w};
            const unsigned int cw_[8] = {C0.x,C0.y,C0.z,C0.w,C1.x,C1.y,C1.z,C1.w};
            float p = 0.f;
            #pragma unroll
            for (int j = 0; j < 16; ++j) {
                const float Bn = (j & 1) ? bfu_hi(bw[j >> 1]) : bfu_lo(bw[j >> 1]);
                const float Cn = (j & 1) ? bfu_hi(cw_[j >> 1]) : bfu_lo(cw_[j >> 1]);
                h[j] = exp2f(dl * A2[j]) * h[j] + dlul * Bn;
                p += h[j] * Cn;
            }
            const float vv = bf2f(uv[tok * (2*D_INNER) + D_INNER + d]);
            uv[tok * (2*D_INNER) + d] = f2bf((p + ul * Dd) * (vv / (1.f + __expf(-vv))));
        }
    }
}

extern "C" void kernel_launch(void* const* d_in, const int* in_sizes, int n_in,
                              void* d_out, int out_size, void* d_ws, size_t ws_size,
                              hipStream_t stream)
{
    const void* x      = d_in[0];
    const void* ln_g   = d_in[1];
    const void* ln_b   = d_in[2];
    const void* W_in   = d_in[3];
    const void* conv_w = d_in[4];
    const void* conv_b = d_in[5];
    const void* W_xp   = d_in[6];
    const void* W_dt   = d_in[7];
    const void* b_dt   = d_in[8];
    const void* log_A  = d_in[9];
    const void* D_par  = d_in[10];
    const void* W_out  = d_in[11];

    // workspace (~93 MB): flag | xn | uv | us | xdbl | delta | carryH | carryA |
    //                     WtIn | WtXp | WtDt | WtOut | xdblF
    int* flag  = (int*)d_ws;
    u16* ws    = (u16*)((char*)d_ws + 512);
    u16* xn    = ws;
    u16* uv    = xn + (size_t)TT * D_MODEL;
    u16* us    = uv + (size_t)TT * 2 * D_INNER;
    u16* xdbl  = us + (size_t)TT * D_INNER;
    u16* delta = xdbl + (size_t)TT * 128;
    float* carryH = (float*)(delta + (size_t)TT * D_INNER);
    float* carryA = carryH + (size_t)BB * NC * D_INNER * D_STATE;
    u16* WtIn  = (u16*)(carryA + (size_t)BB * NC * D_INNER * D_STATE);
    u16* WtXp  = WtIn  + (size_t)2 * D_INNER * D_MODEL;
    u16* WtDt  = WtXp  + (size_t)(DT_RANK + 2 * D_STATE) * D_INNER;
    u16* WtOut = WtDt  + (size_t)D_INNER * DT_RANK;
    float* xdblF = (float*)(WtOut + (size_t)D_MODEL * D_INNER);

    detect_kernel<<<1, 256, 0, stream>>>(x, flag);
    transpose_all_kernel<<<960, 256, 0, stream>>>(
        W_in, W_xp, W_dt, W_out, WtIn, WtXp, WtDt, WtOut, flag);
    hipMemsetAsync(xdblF, 0, (size_t)TT * 128 * sizeof(float), stream);

    ln_kernel<<<TT, 256, 0, stream>>>(x, ln_g, ln_b, xn, flag);
    // uv = xn @ W_in  (4096x3072, K=768)  [128x128, 768 blocks]
    mfma_gemm128<0><<<dim3(2 * D_INNER / 128, TT / 128), 256, 0, stream>>>(
        xn, WtIn, uv, nullptr, flag, D_MODEL, D_MODEL, D_MODEL, 2 * D_INNER);
    // us = silu(causal_conv(uv[:, :1536]))
    conv_silu_kernel<<<(TT * D_INNER) / 256, 256, 0, stream>>>(uv, conv_w, conv_b, us, flag);
    // xdbl = us @ W_xproj  (4096x128, K=1536)  [64x64, split-K x4]
    mfma_gemm<3><<<dim3(2, TT / 64, SKK), 256, 0, stream>>>(
        us, WtXp, nullptr, nullptr, nullptr, xdblF, flag,
        D_INNER / SKK, D_INNER, D_INNER, 128);
    convert_kernel<<<(TT * 128 + 255) / 256, 256, 0, stream>>>(xdblF, xdbl, TT * 128);
    // delta = softplus(xdbl[:, :96] @ W_dt + b_dt)  (4096x1536, K=96)  [128x128]
    mfma_gemm128<1><<<dim3(D_INNER / 128, TT / 128), 256, 0, stream>>>(
        xdbl, WtDt, delta, b_dt, flag, DT_RANK, 128, DT_RANK, D_INNER);
    // chunked selective scan (full-d threads: 768 blocks per pass)
    scan1_kernel<<<dim3(D_INNER / 256, NC, BB), 256, 0, stream>>>(
        delta, us, xdbl, log_A, carryA, carryH, flag);
    scan2_kernel<<<(BB * D_INNER * D_STATE) / 256, 256, 0, stream>>>(carryA, carryH);
    scan3_kernel<<<dim3(D_INNER / 256, NC, BB), 256, 0, stream>>>(
        delta, us, xdbl, uv, log_A, D_par, carryH, flag);
    // out = y @ W_out + x  (4096x768, K=1536)  [64x64, 768 blocks]
    mfma_gemm<2><<<dim3(D_MODEL / 64, TT / 64, 1), 256, 0, stream>>>(
        uv, WtOut, nullptr, d_out, x, nullptr, flag,
        D_INNER, 2 * D_INNER, D_INNER, D_MODEL);
}

// Round 14
// 325.845 us; speedup vs baseline: 1.2183x; 1.2010x over previous
//
#include <hip/hip_runtime.h>

#define D_MODEL 768
#define D_INNER 1536
#define D_STATE 16
#define DT_RANK 96
#define BB 2
#define LL 2048
#define TT (BB*LL)          // 4096 tokens
#define NC 64               // chunks per sequence
#define CL 32               // chunk length
#define SKK 4               // split-K factor for xdbl GEMM
#define LOG2E 1.44269504f

typedef unsigned short u16;
typedef short bf16x8 __attribute__((ext_vector_type(8)));
typedef unsigned short u16x8 __attribute__((ext_vector_type(8)));
typedef float f32x4  __attribute__((ext_vector_type(4)));

__device__ __forceinline__ float bf2f(u16 u) {
    union { unsigned int i; float f; } c; c.i = ((unsigned int)u) << 16; return c.f;
}
__device__ __forceinline__ u16 f2bf(float f) {
    union { float f; unsigned int i; } c; c.f = f;
    unsigned int x = c.i;
    return (u16)((x + 0x7fffu + ((x >> 16) & 1u)) >> 16);   // RNE
}
__device__ __forceinline__ float bfu_lo(unsigned int u) {
    union { unsigned int i; float f; } c; c.i = u << 16; return c.f;
}
__device__ __forceinline__ float bfu_hi(unsigned int u) {
    union { unsigned int i; float f; } c; c.i = u & 0xFFFF0000u; return c.f;
}
__device__ __forceinline__ float ldx(const void* p, size_t i, bool f32) {
    return f32 ? ((const float*)p)[i] : bf2f(((const u16*)p)[i]);
}

// ---- dtype detect: if buffer is fp32, even-index u16s are mantissa-low garbage ----
__global__ void detect_kernel(const void* x, int* flag)
{
    __shared__ int bad;
    if (threadIdx.x == 0) bad = 0;
    __syncthreads();
    const u16* p = (const u16*)x;
    int local = 0;
    for (int i = threadIdx.x; i < 2048; i += 256) {
        const float v = bf2f(p[2 * i]);
        if (!(fabsf(v) < 1e4f)) local = 1;
    }
    if (local) atomicOr(&bad, 1);
    __syncthreads();
    if (threadIdx.x == 0) *flag = bad;       // 1 => inputs are fp32
}

// ---- fused weight transpose: 4 jobs in one launch, 64x64 LDS tiles ----
__global__ __launch_bounds__(256) void transpose_all_kernel(
    const void* __restrict__ W_in, const void* __restrict__ W_xp,
    const void* __restrict__ W_dt, const void* __restrict__ W_out,
    u16* __restrict__ WtIn, u16* __restrict__ WtXp,
    u16* __restrict__ WtDt, u16* __restrict__ WtOut,
    const int* __restrict__ flagp)
{
    const bool f32 = (*flagp != 0);
    int bid = blockIdx.x;
    const void* src; u16* dst; int K, N, bx, by;
    if (bid < 576)      { src = W_in;  dst = WtIn;  K = 768;  N = 3072; bx = bid % 48; by = bid / 48; }
    else if (bid < 624) { bid -= 576; src = W_xp;  dst = WtXp;  K = 1536; N = 128;  bx = bid % 2;  by = bid / 2; }
    else if (bid < 672) { bid -= 624; src = W_dt;  dst = WtDt;  K = 96;   N = 1536; bx = bid % 24; by = bid / 24; }
    else                { bid -= 672; src = W_out; dst = WtOut; K = 1536; N = 768;  bx = bid % 12; by = bid / 12; }
    __shared__ u16 tile[64][72];
    const int t  = threadIdx.x;
    const int n0 = bx * 64, k0 = by * 64;
    {
        const int r = t >> 2, c = (t & 3) * 16;     // tile-local (k, n)
        const int k = k0 + r;
        if (k < K) {
            #pragma unroll
            for (int i = 0; i < 16; ++i)
                tile[r][c + i] = f2bf(ldx(src, (size_t)k * N + n0 + c + i, f32));
        }
    }
    __syncthreads();
    {
        const int nl = t >> 2, kl = (t & 3) * 16;   // tile-local (n, k)
        const int n = n0 + nl;
        #pragma unroll
        for (int i = 0; i < 16; ++i) {
            const int k = k0 + kl + i;
            if (k < K) dst[(size_t)n * K + k] = tile[kl + i][nl];
        }
    }
}

// ---------------- LayerNorm: x (T,768) -> xn (T,768) bf16 ----------------
__global__ __launch_bounds__(256) void ln_kernel(const void* __restrict__ x,
    const void* __restrict__ g, const void* __restrict__ b, u16* __restrict__ xn,
    const int* __restrict__ flagp)
{
    const bool f32 = (*flagp != 0);
    const int tok = blockIdx.x;
    const int tid = threadIdx.x;
    const size_t base = (size_t)tok * D_MODEL;
    float v[3];
    v[0] = ldx(x, base + tid, f32);
    v[1] = ldx(x, base + tid + 256, f32);
    v[2] = ldx(x, base + tid + 512, f32);
    float s = v[0] + v[1] + v[2];
    float q = v[0]*v[0] + v[1]*v[1] + v[2]*v[2];
    #pragma unroll
    for (int o = 32; o > 0; o >>= 1) {
        s += __shfl_down(s, o, 64);
        q += __shfl_down(q, o, 64);
    }
    __shared__ float ss[4], qq[4];
    if ((tid & 63) == 0) { ss[tid >> 6] = s; qq[tid >> 6] = q; }
    __syncthreads();
    const float S = ss[0] + ss[1] + ss[2] + ss[3];
    const float Q = qq[0] + qq[1] + qq[2] + qq[3];
    const float mu  = S * (1.f / D_MODEL);
    const float var = Q * (1.f / D_MODEL) - mu * mu;
    const float rs  = rsqrtf(var + 1e-5f);
    u16* outr = xn + base;
    #pragma unroll
    for (int i = 0; i < 3; ++i) {
        const int c = tid + i * 256;
        outr[c] = f2bf((v[i] - mu) * rs * ldx(g, c, f32) + ldx(b, c, f32));
    }
}

// ------- MFMA GEMM 64x64 tile, BK=32, 4 waves; A (M,K) bf16, Bt (N,K) bf16 -------
// ds_write staging (R8-proven). EPI 0: bf16 store. EPI 1: softplus(acc+bias[col]).
// EPI 2: + res[idx] (flex), flex store. EPI 3: atomicAdd fp32 (split-K).
#define SA 40
template<int EPI>
__global__ __launch_bounds__(256) void mfma_gemm(
    const u16* __restrict__ A, const u16* __restrict__ Bt,
    u16* __restrict__ C, void* __restrict__ Cout, const void* __restrict__ aux,
    float* __restrict__ Cf, const int* __restrict__ flagp,
    int Kslice, int lda, int ldbt, int ldc)
{
    const bool f32 = (*flagp != 0);
    __shared__ u16 As[64 * SA];
    __shared__ u16 Bs[64 * SA];
    const int tid  = threadIdx.x;
    const int wave = tid >> 6, lane = tid & 63;
    const int lrow = lane & 15, quad = lane >> 4;
    const int row0 = blockIdx.y * 64, col0 = blockIdx.x * 64;
    const int k0   = blockIdx.z * Kslice;
    const int sr = tid >> 2, sk = (tid & 3) * 8;    // staging: (row, k-chunk)
    f32x4 acc[4] = {{0.f,0.f,0.f,0.f},{0.f,0.f,0.f,0.f},{0.f,0.f,0.f,0.f},{0.f,0.f,0.f,0.f}};
    for (int kt = k0; kt < k0 + Kslice; kt += 32) {
        *(u16x8*)(&As[sr * SA + sk]) = *(const u16x8*)(A  + (size_t)(row0 + sr) * lda  + kt + sk);
        *(u16x8*)(&Bs[sr * SA + sk]) = *(const u16x8*)(Bt + (size_t)(col0 + sr) * ldbt + kt + sk);
        __syncthreads();
        const bf16x8 af = *(const bf16x8*)(&As[(wave * 16 + lrow) * SA + quad * 8]);
        #pragma unroll
        for (int t = 0; t < 4; ++t) {
            const bf16x8 bf_ = *(const bf16x8*)(&Bs[(t * 16 + lrow) * SA + quad * 8]);
            acc[t] = __builtin_amdgcn_mfma_f32_16x16x32_bf16(af, bf_, acc[t], 0, 0, 0);
        }
        __syncthreads();
    }
    #pragma unroll
    for (int t = 0; t < 4; ++t) {
        #pragma unroll
        for (int r = 0; r < 4; ++r) {
            const int row = row0 + wave * 16 + quad * 4 + r;   // C/D: row=quad*4+reg
            const int col = col0 + t * 16 + lrow;              //      col=lane&15
            const size_t idx = (size_t)row * ldc + col;
            float vv = acc[t][r];
            if (EPI == 1) {
                vv += ldx(aux, col, f32);
                vv = (vv > 20.f) ? vv : log1pf(__expf(vv));
                C[idx] = f2bf(vv);
            } else if (EPI == 2) {
                vv += ldx(aux, idx, f32);
                if (f32) ((float*)Cout)[idx] = vv;
                else     ((u16*)Cout)[idx]   = f2bf(vv);
            } else if (EPI == 3) {
                atomicAdd(&Cf[idx], vv);
            } else {
                C[idx] = f2bf(vv);
            }
        }
    }
}

// ------- MFMA GEMM 128x128 tile, BK=32, 4 waves (2x2); ds_write staging (R8) -------
// EPI 0: bf16 store. EPI 1: softplus(acc + bias[col]) bf16 store.
template<int EPI>
__global__ __launch_bounds__(256) void mfma_gemm128(
    const u16* __restrict__ A, const u16* __restrict__ Bt,
    u16* __restrict__ C, const void* __restrict__ aux,
    const int* __restrict__ flagp,
    int K, int lda, int ldbt, int ldc)
{
    const bool f32 = (*flagp != 0);
    __shared__ u16 As[128 * SA];
    __shared__ u16 Bs[128 * SA];
    const int tid  = threadIdx.x;
    const int wave = tid >> 6, lane = tid & 63;
    const int lrow = lane & 15, quad = lane >> 4;
    const int wy = wave >> 1, wx = wave & 1;
    const int row0 = blockIdx.y * 128, col0 = blockIdx.x * 128;
    const int sr = tid >> 1, sk = (tid & 1) * 16;   // staging: (row, k-half)
    f32x4 acc[4][4];
    #pragma unroll
    for (int i = 0; i < 4; ++i)
        #pragma unroll
        for (int j = 0; j < 4; ++j) acc[i][j] = (f32x4){0.f,0.f,0.f,0.f};
    for (int kt = 0; kt < K; kt += 32) {
        *(u16x8*)(&As[sr * SA + sk])     = *(const u16x8*)(A  + (size_t)(row0 + sr) * lda  + kt + sk);
        *(u16x8*)(&As[sr * SA + sk + 8]) = *(const u16x8*)(A  + (size_t)(row0 + sr) * lda  + kt + sk + 8);
        *(u16x8*)(&Bs[sr * SA + sk])     = *(const u16x8*)(Bt + (size_t)(col0 + sr) * ldbt + kt + sk);
        *(u16x8*)(&Bs[sr * SA + sk + 8]) = *(const u16x8*)(Bt + (size_t)(col0 + sr) * ldbt + kt + sk + 8);
        __syncthreads();
        bf16x8 af[4], bf_[4];
        #pragma unroll
        for (int i = 0; i < 4; ++i)
            af[i] = *(const bf16x8*)(&As[(wy * 64 + i * 16 + lrow) * SA + quad * 8]);
        #pragma unroll
        for (int j = 0; j < 4; ++j)
            bf_[j] = *(const bf16x8*)(&Bs[(wx * 64 + j * 16 + lrow) * SA + quad * 8]);
        #pragma unroll
        for (int i = 0; i < 4; ++i)
            #pragma unroll
            for (int j = 0; j < 4; ++j)
                acc[i][j] = __builtin_amdgcn_mfma_f32_16x16x32_bf16(af[i], bf_[j], acc[i][j], 0, 0, 0);
        __syncthreads();
    }
    #pragma unroll
    for (int i = 0; i < 4; ++i) {
        #pragma unroll
        for (int j = 0; j < 4; ++j) {
            #pragma unroll
            for (int r = 0; r < 4; ++r) {
                const int row = row0 + wy * 64 + i * 16 + quad * 4 + r;
                const int col = col0 + wx * 64 + j * 16 + lrow;
                const size_t idx = (size_t)row * ldc + col;
                float vv = acc[i][j][r];
                if (EPI == 1) {
                    vv += ldx(aux, col, f32);
                    vv = (vv > 20.f) ? vv : log1pf(__expf(vv));
                }
                C[idx] = f2bf(vv);
            }
        }
    }
}

// -------- split-K finalize: xdbl = bf16(xdblF) --------
__global__ __launch_bounds__(256) void convert_kernel(const float* __restrict__ src,
                                                      u16* __restrict__ dst, int n)
{
    const int i = blockIdx.x * 256 + threadIdx.x;
    if (i < n) dst[i] = f2bf(src[i]);
}

// ---- causal depthwise conv (width 4, left-pad 3) + SiLU: uv[:, :1536] -> us ----
__global__ __launch_bounds__(256) void conv_silu_kernel(
    const u16* __restrict__ uv, const void* __restrict__ cw, const void* __restrict__ cb,
    u16* __restrict__ us, const int* __restrict__ flagp)
{
    const bool f32 = (*flagp != 0);
    const int idx = blockIdx.x * 256 + threadIdx.x;
    const int d   = idx % D_INNER;
    const int tok = idx / D_INNER;
    const int l   = tok & (LL - 1);
    float acc = ldx(cb, d, f32);
    #pragma unroll
    for (int j = 0; j < 4; ++j) {
        const int li = l - 3 + j;
        if (li >= 0)
            acc += bf2f(uv[(size_t)(tok - 3 + j) * (2*D_INNER) + d]) * ldx(cw, d * 4 + j, f32);
    }
    us[idx] = f2bf(acc / (1.f + __expf(-acc)));
}

// ----- scan pass 1: per-chunk local scan -> carries; one thread owns a full d -----
// a_j = a_1^(j+1) when A2[j] = (j+1)*A2[0] (Mamba A-init) -> 1 exp2 + 15 muls per t.
__global__ __launch_bounds__(256) void scan1_kernel(
    const u16* __restrict__ delta, const u16* __restrict__ us,
    const u16* __restrict__ xdbl, const void* __restrict__ log_A,
    float* __restrict__ carryA, float* __restrict__ carryH,
    const int* __restrict__ flagp)
{
    const bool f32 = (*flagp != 0);
    const int d = blockIdx.x * 256 + threadIdx.x;
    const int c = blockIdx.y, b = blockIdx.z;
    float A2[16], h[16];
    #pragma unroll
    for (int j = 0; j < 16; ++j) {
        A2[j] = -__expf(ldx(log_A, d * D_STATE + j, f32)) * LOG2E;
        h[j] = 0.f;
    }
    bool pw = true;
    #pragma unroll
    for (int j = 1; j < 16; ++j)
        pw = pw && (fabsf(A2[j] - (j + 1) * A2[0]) <= 0.02f * (j + 1) * fabsf(A2[0]));
    float sdl = 0.f;
    size_t tok = (size_t)b * LL + c * CL;
    if (pw) {
        #pragma unroll 2
        for (int t = 0; t < CL; ++t, ++tok) {
            const float dl = bf2f(delta[tok * D_INNER + d]);
            const float ul = bf2f(us[tok * D_INNER + d]);
            const uint4 B0 = *(const uint4*)(xdbl + tok * 128 + DT_RANK);
            const uint4 B1 = *(const uint4*)(xdbl + tok * 128 + DT_RANK + 8);
            const float dlul = dl * ul;
            sdl += dl;
            const unsigned int bw[8] = {B0.x,B0.y,B0.z,B0.w,B1.x,B1.y,B1.z,B1.w};
            const float a1 = exp2f(dl * A2[0]);
            float aj = 1.f;
            #pragma unroll
            for (int j = 0; j < 16; ++j) {
                aj *= a1;
                const float Bn = (j & 1) ? bfu_hi(bw[j >> 1]) : bfu_lo(bw[j >> 1]);
                h[j] = aj * h[j] + dlul * Bn;
            }
        }
    } else {
        #pragma unroll 2
        for (int t = 0; t < CL; ++t, ++tok) {
            const float dl = bf2f(delta[tok * D_INNER + d]);
            const float ul = bf2f(us[tok * D_INNER + d]);
            const uint4 B0 = *(const uint4*)(xdbl + tok * 128 + DT_RANK);
            const uint4 B1 = *(const uint4*)(xdbl + tok * 128 + DT_RANK + 8);
            const float dlul = dl * ul;
            sdl += dl;
            const unsigned int bw[8] = {B0.x,B0.y,B0.z,B0.w,B1.x,B1.y,B1.z,B1.w};
            #pragma unroll
            for (int j = 0; j < 16; ++j) {
                const float Bn = (j & 1) ? bfu_hi(bw[j >> 1]) : bfu_lo(bw[j >> 1]);
                h[j] = exp2f(dl * A2[j]) * h[j] + dlul * Bn;
            }
        }
    }
    const size_t ci = (((size_t)b * NC + c) * D_INNER + d) * D_STATE;
    #pragma unroll
    for (int q = 0; q < 4; ++q) {
        *(float4*)(carryA + ci + 4*q) = (float4){
            exp2f(A2[4*q+0]*sdl), exp2f(A2[4*q+1]*sdl),
            exp2f(A2[4*q+2]*sdl), exp2f(A2[4*q+3]*sdl)};
        *(float4*)(carryH + ci + 4*q) = (float4){h[4*q+0], h[4*q+1], h[4*q+2], h[4*q+3]};
    }
}

// -------- scan pass 2: exclusive scan over chunk carries, in place on carryH --------
__global__ __launch_bounds__(256) void scan2_kernel(
    const float* __restrict__ carryA, float* __restrict__ carryH)
{
    const int gid = blockIdx.x * 256 + threadIdx.x;
    const int b   = gid / (D_INNER * D_STATE);
    const int dn  = gid % (D_INNER * D_STATE);
    float hrun = 0.f;
    #pragma unroll
    for (int c = 0; c < NC; ++c) {
        const size_t ci = ((size_t)(b * NC + c) * D_INNER * D_STATE) + dn;
        const float a = carryA[ci], hh = carryH[ci];
        carryH[ci] = hrun;
        hrun = a * hrun + hh;
    }
}

// ------ scan pass 3: re-run chunk seeded with carry; emit gated y; full-d threads ------
__global__ __launch_bounds__(256) void scan3_kernel(
    const u16* __restrict__ delta, const u16* __restrict__ us,
    const u16* __restrict__ xdbl, u16* __restrict__ uv,
    const void* __restrict__ log_A, const void* __restrict__ D_param,
    const float* __restrict__ carryH, const int* __restrict__ flagp)
{
    const bool f32 = (*flagp != 0);
    const int d = blockIdx.x * 256 + threadIdx.x;
    const int c = blockIdx.y, b = blockIdx.z;
    const float Dd = ldx(D_param, d, f32);
    float A2[16], h[16];
    const size_t ci = (((size_t)b * NC + c) * D_INNER + d) * D_STATE;
    #pragma unroll
    for (int j = 0; j < 16; ++j)
        A2[j] = -__expf(ldx(log_A, d * D_STATE + j, f32)) * LOG2E;
    bool pw = true;
    #pragma unroll
    for (int j = 1; j < 16; ++j)
        pw = pw && (fabsf(A2[j] - (j + 1) * A2[0]) <= 0.02f * (j + 1) * fabsf(A2[0]));
    #pragma unroll
    for (int q = 0; q < 4; ++q) {
        const float4 hq = *(const float4*)(carryH + ci + 4*q);
        h[4*q+0] = hq.x; h[4*q+1] = hq.y; h[4*q+2] = hq.z; h[4*q+3] = hq.w;
    }
    size_t tok = (size_t)b * LL + c * CL;
    if (pw) {
        #pragma unroll 2
        for (int t = 0; t < CL; ++t, ++tok) {
            const float dl = bf2f(delta[tok * D_INNER + d]);
            const float ul = bf2f(us[tok * D_INNER + d]);
            const uint4 B0 = *(const uint4*)(xdbl + tok * 128 + DT_RANK);
            const uint4 B1 = *(const uint4*)(xdbl + tok * 128 + DT_RANK + 8);
            const uint4 C0 = *(const uint4*)(xdbl + tok * 128 + DT_RANK + D_STATE);
            const uint4 C1 = *(const uint4*)(xdbl + tok * 128 + DT_RANK + D_STATE + 8);
            const float dlul = dl * ul;
            const unsigned int bw[8] = {B0.x,B0.y,B0.z,B0.w,B1.x,B1.y,B1.z,B1.w};
            const unsigned int cw_[8] = {C0.x,C0.y,C0.z,C0.w,C1.x,C1.y,C1.z,C1.w};
            const float a1 = exp2f(dl * A2[0]);
            float aj = 1.f, p = 0.f;
            #pragma unroll
            for (int j = 0; j < 16; ++j) {
                aj *= a1;
                const float Bn = (j & 1) ? bfu_hi(bw[j >> 1]) : bfu_lo(bw[j >> 1]);
                const float Cn = (j & 1) ? bfu_hi(cw_[j >> 1]) : bfu_lo(cw_[j >> 1]);
                h[j] = aj * h[j] + dlul * Bn;
                p += h[j] * Cn;
            }
            const float vv = bf2f(uv[tok * (2*D_INNER) + D_INNER + d]);
            uv[tok * (2*D_INNER) + d] = f2bf((p + ul * Dd) * (vv / (1.f + __expf(-vv))));
        }
    } else {
        #pragma unroll 2
        for (int t = 0; t < CL; ++t, ++tok) {
            const float dl = bf2f(delta[tok * D_INNER + d]);
            const float ul = bf2f(us[tok * D_INNER + d]);
            const uint4 B0 = *(const uint4*)(xdbl + tok * 128 + DT_RANK);
            const uint4 B1 = *(const uint4*)(xdbl + tok * 128 + DT_RANK + 8);
            const uint4 C0 = *(const uint4*)(xdbl + tok * 128 + DT_RANK + D_STATE);
            const uint4 C1 = *(const uint4*)(xdbl + tok * 128 + DT_RANK + D_STATE + 8);
            const float dlul = dl * ul;
            const unsigned int bw[8] = {B0.x,B0.y,B0.z,B0.w,B1.x,B1.y,B1.z,B1.w};
            const unsigned int cw_[8] = {C0.x,C0.y,C0.z,C0.w,C1.x,C1.y,C1.z,C1.w};
            float p = 0.f;
            #pragma unroll
            for (int j = 0; j < 16; ++j) {
                const float Bn = (j & 1) ? bfu_hi(bw[j >> 1]) : bfu_lo(bw[j >> 1]);
                const float Cn = (j & 1) ? bfu_hi(cw_[j >> 1]) : bfu_lo(cw_[j >> 1]);
                h[j] = exp2f(dl * A2[j]) * h[j] + dlul * Bn;
                p += h[j] * Cn;
            }
            const float vv = bf2f(uv[tok * (2*D_INNER) + D_INNER + d]);
            uv[tok * (2*D_INNER) + d] = f2bf((p + ul * Dd) * (vv / (1.f + __expf(-vv))));
        }
    }
}

extern "C" void kernel_launch(void* const* d_in, const int* in_sizes, int n_in,
                              void* d_out, int out_size, void* d_ws, size_t ws_size,
                              hipStream_t stream)
{
    const void* x      = d_in[0];
    const void* ln_g   = d_in[1];
    const void* ln_b   = d_in[2];
    const void* W_in   = d_in[3];
    const void* conv_w = d_in[4];
    const void* conv_b = d_in[5];
    const void* W_xp   = d_in[6];
    const void* W_dt   = d_in[7];
    const void* b_dt   = d_in[8];
    const void* log_A  = d_in[9];
    const void* D_par  = d_in[10];
    const void* W_out  = d_in[11];

    // workspace (~93 MB): flag | xn | uv | us | xdbl | delta | carryH | carryA |
    //                     WtIn | WtXp | WtDt | WtOut | xdblF
    int* flag  = (int*)d_ws;
    u16* ws    = (u16*)((char*)d_ws + 512);
    u16* xn    = ws;
    u16* uv    = xn + (size_t)TT * D_MODEL;
    u16* us    = uv + (size_t)TT * 2 * D_INNER;
    u16* xdbl  = us + (size_t)TT * D_INNER;
    u16* delta = xdbl + (size_t)TT * 128;
    float* carryH = (float*)(delta + (size_t)TT * D_INNER);
    float* carryA = carryH + (size_t)BB * NC * D_INNER * D_STATE;
    u16* WtIn  = (u16*)(carryA + (size_t)BB * NC * D_INNER * D_STATE);
    u16* WtXp  = WtIn  + (size_t)2 * D_INNER * D_MODEL;
    u16* WtDt  = WtXp  + (size_t)(DT_RANK + 2 * D_STATE) * D_INNER;
    u16* WtOut = WtDt  + (size_t)D_INNER * DT_RANK;
    float* xdblF = (float*)(WtOut + (size_t)D_MODEL * D_INNER);

    detect_kernel<<<1, 256, 0, stream>>>(x, flag);
    transpose_all_kernel<<<960, 256, 0, stream>>>(
        W_in, W_xp, W_dt, W_out, WtIn, WtXp, WtDt, WtOut, flag);
    hipMemsetAsync(xdblF, 0, (size_t)TT * 128 * sizeof(float), stream);

    ln_kernel<<<TT, 256, 0, stream>>>(x, ln_g, ln_b, xn, flag);
    // uv = xn @ W_in  (4096x3072, K=768)  [128x128, 768 blocks]
    mfma_gemm128<0><<<dim3(2 * D_INNER / 128, TT / 128), 256, 0, stream>>>(
        xn, WtIn, uv, nullptr, flag, D_MODEL, D_MODEL, D_MODEL, 2 * D_INNER);
    // us = silu(causal_conv(uv[:, :1536]))
    conv_silu_kernel<<<(TT * D_INNER) / 256, 256, 0, stream>>>(uv, conv_w, conv_b, us, flag);
    // xdbl = us @ W_xproj  (4096x128, K=1536)  [64x64, split-K x4]
    mfma_gemm<3><<<dim3(2, TT / 64, SKK), 256, 0, stream>>>(
        us, WtXp, nullptr, nullptr, nullptr, xdblF, flag,
        D_INNER / SKK, D_INNER, D_INNER, 128);
    convert_kernel<<<(TT * 128 + 255) / 256, 256, 0, stream>>>(xdblF, xdbl, TT * 128);
    // delta = softplus(xdbl[:, :96] @ W_dt + b_dt)  (4096x1536, K=96)
    // [R14: 64x64 tile -> 1536 blocks = 24 waves/CU; was 128x128/384 blocks at 6 waves/CU,
    //  latency-exposed at 108 us with MfmaUtil 0.4%]
    mfma_gemm<1><<<dim3(D_INNER / 64, TT / 64, 1), 256, 0, stream>>>(
        xdbl, WtDt, delta, nullptr, b_dt, nullptr, flag,
        DT_RANK, 128, DT_RANK, D_INNER);
    // chunked selective scan (full-d threads: 768 blocks per pass)
    scan1_kernel<<<dim3(D_INNER / 256, NC, BB), 256, 0, stream>>>(
        delta, us, xdbl, log_A, carryA, carryH, flag);
    scan2_kernel<<<(BB * D_INNER * D_STATE) / 256, 256, 0, stream>>>(carryA, carryH);
    scan3_kernel<<<dim3(D_INNER / 256, NC, BB), 256, 0, stream>>>(
        delta, us, xdbl, uv, log_A, D_par, carryH, flag);
    // out = y @ W_out + x  (4096x768, K=1536)  [64x64, 768 blocks]
    mfma_gemm<2><<<dim3(D_MODEL / 64, TT / 64, 1), 256, 0, stream>>>(
        uv, WtOut, nullptr, d_out, x, nullptr, flag,
        D_INNER, 2 * D_INNER, D_INNER, D_MODEL);
}